// Round 1
// baseline (732.919 us; speedup 1.0000x reference)
//
#include <hip/hip_runtime.h>
#include <stdint.h>

#define BB 16384
#define ZZ 64
#define DD 66
#define NB 2          // batch rows per wave
#define WPB 4         // waves per block
#define ROWS (WPB*NB) // 8 rows per block

// ---- ws float offsets (filled by prep kernel every launch) ----
#define OFF_SVMU 0            // [66][64] float2 (mult_u, sqrt(var_u)) -> 8448 floats
#define OFF_C0U  8448         // 64 : -0.5*sum_d(1+lv-var) per z
#define OFF_MG   8512         // 64
#define OFF_SVG  8576         // 64
#define OFF_C0G  8640         // 1
#define OFF_W1T  8704         // [66][4][64][4] floats = 67584 (coalesced W1)
#define OFF_W2T  76288        // [16][4][64][4] floats = 16384 (coalesced W2)
#define OFF_W3T  92672        // [8][64][4]    floats = 2048  (coalesced W3)

// Fold exps/constants + transpose weights into lane-coalesced layouts.
// grid = 66 blocks; block d handles W1 slice d (+ extra roles for low blocks).
__global__ void prep_kernel(const float* __restrict__ mult_u, const float* __restrict__ logvar_u,
                            const float* __restrict__ mult_g, const float* __restrict__ logvar_g,
                            const float* __restrict__ W1, const float* __restrict__ W2,
                            const float* __restrict__ W3, float* __restrict__ ws) {
  const int d = blockIdx.x;   // 0..65
  const int t = threadIdx.x;
  const int z = t >> 2, q = t & 3;

  // W1 transpose: W1T[((d*4+q)*64+z)*4 + j] = W1[(z*DD+d)*16 + q*4 + j]
  {
    const float4 v = *reinterpret_cast<const float4*>(W1 + (z*DD + d)*16 + q*4);
    *reinterpret_cast<float4*>(ws + OFF_W1T + ((d*4 + q)*64 + z)*4) = v;
  }
  if (t < ZZ) {
    ws[OFF_SVMU + 2*(d*ZZ + t)]     = mult_u[d*ZZ + t];
    ws[OFF_SVMU + 2*(d*ZZ + t) + 1] = __expf(0.5f * logvar_u[d*ZZ + t]);
  }
  if (d < 16) {  // W2 transpose, h = d
    const float4 v = *reinterpret_cast<const float4*>(W2 + (z*16 + d)*16 + q*4);
    *reinterpret_cast<float4*>(ws + OFF_W2T + ((d*4 + q)*64 + z)*4) = v;
  }
  if (d == 16 || d == 17) {  // W3 transpose
    const int idx = (d - 16)*256 + t;   // 0..511
    const int qq = idx >> 6, zz = idx & 63;
    const float4 v = *reinterpret_cast<const float4*>(W3 + zz*32 + qq*4);
    *reinterpret_cast<float4*>(ws + OFF_W3T + (qq*64 + zz)*4) = v;
  }
  if (d == 0) {
    if (t < ZZ) {
      float s = 0.f;
      for (int dd = 0; dd < DD; ++dd) {
        const float lv = logvar_u[dd*ZZ + t];
        s += 1.f + lv - __expf(lv);
      }
      ws[OFF_C0U + t] = -0.5f * s;
      ws[OFF_MG  + t] = mult_g[t];
      ws[OFF_SVG + t] = __expf(0.5f * logvar_g[t]);
    }
    if (t == 0) {
      float s = 0.f;
      for (int zc = 0; zc < ZZ; ++zc) {
        const float lv = logvar_g[zc];
        s += 1.f + lv - __expf(lv);
      }
      ws[OFF_C0G] = -0.5f * s;
    }
  }
}

// Main: lane = z; wave handles NB batch rows. Explicit register pipeline in the
// d-loop (noise 2 ahead, weights/x 1 ahead); choice MLP fused at block level.
__global__ __launch_bounds__(256, 4)
void disrnn_main(const float* __restrict__ latents, const float* __restrict__ obs,
                 const float* __restrict__ noise_u, const float* __restrict__ noise_g,
                 const float* __restrict__ z0, const float* __restrict__ b1,
                 const float* __restrict__ b2, const float* __restrict__ b3,
                 const float* __restrict__ Wc1, const float* __restrict__ bc1,
                 const float* __restrict__ Wc2, const float* __restrict__ bc2,
                 const float* __restrict__ Wc3, const float* __restrict__ bc3,
                 const float* __restrict__ ws, const int* __restrict__ t0p,
                 float* __restrict__ out) {
  float* out_zt = out + BB*2;
  float* out_kg = out + BB*2 + BB*ZZ;
  float* out_ku = out + BB*2 + BB*ZZ + BB;

  __shared__ float x_lds[WPB][NB][68];
  __shared__ float ztl[ROWS][64];
  __shared__ float y1[ROWS][32];
  __shared__ float y2[ROWS][32];

  const int tid  = threadIdx.x;
  const int w    = tid >> 6;
  const int lane = tid & 63;
  const int b0   = (blockIdx.x * WPB + w) * NB;
  const int t0   = *t0p;

#pragma unroll
  for (int i = 0; i < NB; ++i) {
    x_lds[w][i][lane] = t0 ? z0[lane] : latents[(b0 + i)*ZZ + lane];
    if (lane < 2) x_lds[w][i][ZZ + lane] = obs[(b0 + i)*2 + lane];
  }
  __syncthreads();

  const float c0u_l = ws[OFF_C0U + lane];
  const float mg_l  = ws[OFF_MG + lane];
  const float svg_l = ws[OFF_SVG + lane];
  const float c0g   = ws[OFF_C0G];

  float acc[NB][16], kacc[NB];
  {
    const float4* bp = reinterpret_cast<const float4*>(b1 + lane*16);
    float b1r[16];
#pragma unroll
    for (int q = 0; q < 4; ++q) {
      const float4 v = bp[q];
      b1r[4*q] = v.x; b1r[4*q+1] = v.y; b1r[4*q+2] = v.z; b1r[4*q+3] = v.w;
    }
#pragma unroll
    for (int i = 0; i < NB; ++i) {
      kacc[i] = 0.f;
#pragma unroll
      for (int h = 0; h < 16; ++h) acc[i][h] = b1r[h];
    }
  }

  const float*  w1t  = ws + OFF_W1T;
  const float2* svmu = reinterpret_cast<const float2*>(ws + OFF_SVMU);
  const float* np[NB];
#pragma unroll
  for (int i = 0; i < NB; ++i) np[i] = noise_u + (b0 + i)*DD*ZZ + lane;

  // ---- pipeline prologue ----
  float nv_c[NB], nv_n[NB];
#pragma unroll
  for (int i = 0; i < NB; ++i) { nv_c[i] = np[i][0]; nv_n[i] = np[i][ZZ]; }
  float wv_c[16];
#pragma unroll
  for (int q = 0; q < 4; ++q) {
    const float4 v = *reinterpret_cast<const float4*>(w1t + (q*64 + lane)*4);
    wv_c[4*q] = v.x; wv_c[4*q+1] = v.y; wv_c[4*q+2] = v.z; wv_c[4*q+3] = v.w;
  }
  float2 sm_c = svmu[lane];
  float xv_c[NB];
#pragma unroll
  for (int i = 0; i < NB; ++i) xv_c[i] = x_lds[w][i][0];

  // ---- layer 1 over all 66 input dims, software-pipelined ----
#pragma unroll 2
  for (int d = 0; d < DD; ++d) {
    const int dn  = (d + 1 < DD) ? d + 1 : DD - 1;
    const int dnn = (d + 2 < DD) ? d + 2 : DD - 1;
    // issue next loads first (noise depth-2, weights/x depth-1)
    float nv2[NB];
#pragma unroll
    for (int i = 0; i < NB; ++i) nv2[i] = np[i][dnn*ZZ];
    float wv_n[16];
#pragma unroll
    for (int q = 0; q < 4; ++q) {
      const float4 v = *reinterpret_cast<const float4*>(w1t + ((dn*4 + q)*64 + lane)*4);
      wv_n[4*q] = v.x; wv_n[4*q+1] = v.y; wv_n[4*q+2] = v.z; wv_n[4*q+3] = v.w;
    }
    const float2 sm_n = svmu[dn*ZZ + lane];
    float xv_n[NB];
#pragma unroll
    for (int i = 0; i < NB; ++i) xv_n[i] = x_lds[w][i][dn];

    // compute iteration d
#pragma unroll
    for (int i = 0; i < NB; ++i) {
      const float mean = xv_c[i] * sm_c.x;
      kacc[i] = fmaf(mean, mean, kacc[i]);
      const float xt = fmaf(nv_c[i], sm_c.y, mean);
#pragma unroll
      for (int h = 0; h < 16; ++h) acc[i][h] = fmaf(xt, wv_c[h], acc[i][h]);
    }
    // rotate
#pragma unroll
    for (int i = 0; i < NB; ++i) { nv_c[i] = nv_n[i]; nv_n[i] = nv2[i]; xv_c[i] = xv_n[i]; }
#pragma unroll
    for (int h = 0; h < 16; ++h) wv_c[h] = wv_n[h];
    sm_c = sm_n;
  }

  // ---- layer 2 (coalesced W2T) ----
  float h2[NB][16];
  {
    const float4* bp = reinterpret_cast<const float4*>(b2 + lane*16);
    float b2r[16];
#pragma unroll
    for (int q = 0; q < 4; ++q) {
      const float4 v = bp[q];
      b2r[4*q] = v.x; b2r[4*q+1] = v.y; b2r[4*q+2] = v.z; b2r[4*q+3] = v.w;
    }
#pragma unroll
    for (int i = 0; i < NB; ++i) {
#pragma unroll
      for (int h = 0; h < 16; ++h) acc[i][h] = fmaxf(acc[i][h], 0.f);
#pragma unroll
      for (int k = 0; k < 16; ++k) h2[i][k] = b2r[k];
    }
  }
  const float* w2t = ws + OFF_W2T;
#pragma unroll
  for (int h = 0; h < 16; ++h) {
    float wv2[16];
#pragma unroll
    for (int q = 0; q < 4; ++q) {
      const float4 v = *reinterpret_cast<const float4*>(w2t + ((h*4 + q)*64 + lane)*4);
      wv2[4*q] = v.x; wv2[4*q+1] = v.y; wv2[4*q+2] = v.z; wv2[4*q+3] = v.w;
    }
#pragma unroll
    for (int i = 0; i < NB; ++i) {
      const float hv = acc[i][h];
#pragma unroll
      for (int k = 0; k < 16; ++k) h2[i][k] = fmaf(hv, wv2[k], h2[i][k]);
    }
  }

  // ---- layer 3 + gate + kld/z_tilde outputs (coalesced W3T) ----
  float w3r[32];
  {
    const float* w3t = ws + OFF_W3T;
#pragma unroll
    for (int q = 0; q < 8; ++q) {
      const float4 v = *reinterpret_cast<const float4*>(w3t + (q*64 + lane)*4);
      w3r[4*q] = v.x; w3r[4*q+1] = v.y; w3r[4*q+2] = v.z; w3r[4*q+3] = v.w;
    }
  }
  const float2 b3v = reinterpret_cast<const float2*>(b3)[lane];
#pragma unroll
  for (int i = 0; i < NB; ++i) {
    const int b = b0 + i;
    float o0 = b3v.x, o1 = b3v.y;
#pragma unroll
    for (int k = 0; k < 16; ++k) {
      const float hv = fmaxf(h2[i][k], 0.f);
      o0 = fmaf(hv, w3r[2*k], o0);
      o1 = fmaf(hv, w3r[2*k + 1], o1);
    }
    const float xl = x_lds[w][i][lane];
    const float wg = 1.f / (1.f + __expf(-o1));
    const float nl = fmaf(wg, o0 - xl, xl);        // (1-w)*lat + u*w
    const float tg = mg_l * nl;
    const float zt = fmaf(noise_g[b*ZZ + lane], svg_l, tg);
    out_zt[b*ZZ + lane] = zt;
    out_ku[b*ZZ + lane] = fmaf(0.5f, kacc[i], c0u_l);
    ztl[w*NB + i][lane] = zt;
    // kld_g: wave-wide butterfly reduce of tg^2 (no LDS, no barrier)
    float t2 = tg * tg;
#pragma unroll
    for (int off = 32; off; off >>= 1) t2 += __shfl_xor(t2, off);
    if (lane == 0) out_kg[b] = fmaf(0.5f, t2, c0g);
  }
  __syncthreads();

  // ---- fused choice MLP: thread -> (row r, neuron hc); 8 rows x 32 neurons = 256 ----
  const int r  = tid >> 5;
  const int hc = tid & 31;
  {
    float a = bc1[hc];
#pragma unroll
    for (int zc = 0; zc < 64; ++zc) a = fmaf(ztl[r][zc], Wc1[zc*32 + hc], a);
    y1[r][hc] = fmaxf(a, 0.f);
  }
  __syncthreads();
  {
    float a = bc2[hc];
#pragma unroll
    for (int k = 0; k < 32; ++k) a = fmaf(y1[r][k], Wc2[k*32 + hc], a);
    y2[r][hc] = fmaxf(a, 0.f);
  }
  __syncthreads();
  if (tid < ROWS*2) {
    const int rr = tid >> 1, o = tid & 1;
    float s = bc3[o];
#pragma unroll
    for (int k = 0; k < 32; ++k) s = fmaf(y2[rr][k], Wc3[2*k + o], s);
    out[(blockIdx.x*ROWS + rr)*2 + o] = s;
  }
}

extern "C" void kernel_launch(void* const* d_in, const int* in_sizes, int n_in,
                              void* d_out, int out_size, void* d_ws, size_t ws_size,
                              hipStream_t stream) {
  (void)in_sizes; (void)n_in; (void)out_size; (void)ws_size;
  const float* latents  = (const float*)d_in[0];
  const float* obs      = (const float*)d_in[1];
  const float* noise_u  = (const float*)d_in[2];
  const float* noise_g  = (const float*)d_in[3];
  const float* z0       = (const float*)d_in[4];
  const float* mult_u   = (const float*)d_in[5];
  const float* logvar_u = (const float*)d_in[6];
  const float* mult_g   = (const float*)d_in[7];
  const float* logvar_g = (const float*)d_in[8];
  const float* W1       = (const float*)d_in[9];
  const float* b1       = (const float*)d_in[10];
  const float* W2       = (const float*)d_in[11];
  const float* b2       = (const float*)d_in[12];
  const float* W3       = (const float*)d_in[13];
  const float* b3       = (const float*)d_in[14];
  const float* Wc1      = (const float*)d_in[15];
  const float* bc1      = (const float*)d_in[16];
  const float* Wc2      = (const float*)d_in[17];
  const float* bc2      = (const float*)d_in[18];
  const float* Wc3      = (const float*)d_in[19];
  const float* bc3      = (const float*)d_in[20];
  const int*  t0p       = (const int*)d_in[21];
  float* ws   = (float*)d_ws;
  float* outp = (float*)d_out;

  prep_kernel<<<66, 256, 0, stream>>>(mult_u, logvar_u, mult_g, logvar_g, W1, W2, W3, ws);
  disrnn_main<<<BB/ROWS, 256, 0, stream>>>(latents, obs, noise_u, noise_g, z0,
                                           b1, b2, b3, Wc1, bc1, Wc2, bc2, Wc3, bc3,
                                           ws, t0p, outp);
}

// Round 2
// 566.071 us; speedup vs baseline: 1.2947x; 1.2947x over previous
//
#include <hip/hip_runtime.h>
#include <stdint.h>

#define BB 16384
#define ZZ 64
#define DD 66
#define NB 4          // batch rows per wave
#define WPB 4         // waves per block
#define ROWS (WPB*NB) // 16 rows per block

// ---- ws float offsets (filled by prep kernel every launch) ----
#define OFF_SVMU 0            // [66][64] float2 (mult_u, sqrt(var_u)) -> 8448 floats
#define OFF_C0U  8448         // 64 : -0.5*sum_d(1+lv-var) per z
#define OFF_MG   8512         // 64
#define OFF_SVG  8576         // 64
#define OFF_C0G  8640         // 1
#define OFF_W1T  8704         // [66][4][64][4] floats = 67584 (coalesced W1)
#define OFF_W2T  76288        // [16][4][64][4] floats = 16384 (coalesced W2)
#define OFF_W3T  92672        // [8][64][4]    floats = 2048  (coalesced W3)

// Fold exps/constants + transpose weights into lane-coalesced layouts.
__global__ void prep_kernel(const float* __restrict__ mult_u, const float* __restrict__ logvar_u,
                            const float* __restrict__ mult_g, const float* __restrict__ logvar_g,
                            const float* __restrict__ W1, const float* __restrict__ W2,
                            const float* __restrict__ W3, float* __restrict__ ws) {
  const int d = blockIdx.x;   // 0..65
  const int t = threadIdx.x;
  const int z = t >> 2, q = t & 3;

  // W1 transpose: W1T[((d*4+q)*64+z)*4 + j] = W1[(z*DD+d)*16 + q*4 + j]
  {
    const float4 v = *reinterpret_cast<const float4*>(W1 + (z*DD + d)*16 + q*4);
    *reinterpret_cast<float4*>(ws + OFF_W1T + ((d*4 + q)*64 + z)*4) = v;
  }
  if (t < ZZ) {
    ws[OFF_SVMU + 2*(d*ZZ + t)]     = mult_u[d*ZZ + t];
    ws[OFF_SVMU + 2*(d*ZZ + t) + 1] = __expf(0.5f * logvar_u[d*ZZ + t]);
  }
  if (d < 16) {  // W2 transpose, h = d
    const float4 v = *reinterpret_cast<const float4*>(W2 + (z*16 + d)*16 + q*4);
    *reinterpret_cast<float4*>(ws + OFF_W2T + ((d*4 + q)*64 + z)*4) = v;
  }
  if (d == 16 || d == 17) {  // W3 transpose
    const int idx = (d - 16)*256 + t;   // 0..511
    const int qq = idx >> 6, zz = idx & 63;
    const float4 v = *reinterpret_cast<const float4*>(W3 + zz*32 + qq*4);
    *reinterpret_cast<float4*>(ws + OFF_W3T + (qq*64 + zz)*4) = v;
  }
  if (d == 0) {
    if (t < ZZ) {
      float s = 0.f;
      for (int dd = 0; dd < DD; ++dd) {
        const float lv = logvar_u[dd*ZZ + t];
        s += 1.f + lv - __expf(lv);
      }
      ws[OFF_C0U + t] = -0.5f * s;
      ws[OFF_MG  + t] = mult_g[t];
      ws[OFF_SVG + t] = __expf(0.5f * logvar_g[t]);
    }
    if (t == 0) {
      float s = 0.f;
      for (int zc = 0; zc < ZZ; ++zc) {
        const float lv = logvar_g[zc];
        s += 1.f + lv - __expf(lv);
      }
      ws[OFF_C0G] = -0.5f * s;
    }
  }
}

// Main: lane = z; wave handles NB batch rows. Register pipeline in the d-loop
// (noise depth-2, weights/x depth-1); choice MLP fused at block level.
// launch_bounds(256,2): known no-spill setting (round-0 evidence; (256,4) spilled).
__global__ __launch_bounds__(256, 2)
void disrnn_main(const float* __restrict__ latents, const float* __restrict__ obs,
                 const float* __restrict__ noise_u, const float* __restrict__ noise_g,
                 const float* __restrict__ z0, const float* __restrict__ b1,
                 const float* __restrict__ b2, const float* __restrict__ b3,
                 const float* __restrict__ Wc1, const float* __restrict__ bc1,
                 const float* __restrict__ Wc2, const float* __restrict__ bc2,
                 const float* __restrict__ Wc3, const float* __restrict__ bc3,
                 const float* __restrict__ ws, const int* __restrict__ t0p,
                 float* __restrict__ out) {
  float* out_zt = out + BB*2;
  float* out_kg = out + BB*2 + BB*ZZ;
  float* out_ku = out + BB*2 + BB*ZZ + BB;

  __shared__ float x_lds[WPB][NB][68];
  __shared__ float ztl[ROWS][64];
  __shared__ float y1[ROWS][32];
  __shared__ float y2[ROWS][32];

  const int tid  = threadIdx.x;
  const int w    = tid >> 6;
  const int lane = tid & 63;
  const int b0   = (blockIdx.x * WPB + w) * NB;
  const int t0   = *t0p;

#pragma unroll
  for (int i = 0; i < NB; ++i) {
    x_lds[w][i][lane] = t0 ? z0[lane] : latents[(b0 + i)*ZZ + lane];
    if (lane < 2) x_lds[w][i][ZZ + lane] = obs[(b0 + i)*2 + lane];
  }
  __syncthreads();

  const float c0u_l = ws[OFF_C0U + lane];
  const float mg_l  = ws[OFF_MG + lane];
  const float svg_l = ws[OFF_SVG + lane];
  const float c0g   = ws[OFF_C0G];

  float acc[NB][16], kacc[NB];
  {
    const float4* bp = reinterpret_cast<const float4*>(b1 + lane*16);
    float b1r[16];
#pragma unroll
    for (int q = 0; q < 4; ++q) {
      const float4 v = bp[q];
      b1r[4*q] = v.x; b1r[4*q+1] = v.y; b1r[4*q+2] = v.z; b1r[4*q+3] = v.w;
    }
#pragma unroll
    for (int i = 0; i < NB; ++i) {
      kacc[i] = 0.f;
#pragma unroll
      for (int h = 0; h < 16; ++h) acc[i][h] = b1r[h];
    }
  }

  const float*  w1t  = ws + OFF_W1T;
  const float2* svmu = reinterpret_cast<const float2*>(ws + OFF_SVMU);
  const float* np[NB];
#pragma unroll
  for (int i = 0; i < NB; ++i) np[i] = noise_u + (b0 + i)*DD*ZZ + lane;

  // ---- pipeline prologue ----
  float nv_c[NB], nv_n[NB];
#pragma unroll
  for (int i = 0; i < NB; ++i) { nv_c[i] = np[i][0]; nv_n[i] = np[i][ZZ]; }
  float wv_c[16];
#pragma unroll
  for (int q = 0; q < 4; ++q) {
    const float4 v = *reinterpret_cast<const float4*>(w1t + (q*64 + lane)*4);
    wv_c[4*q] = v.x; wv_c[4*q+1] = v.y; wv_c[4*q+2] = v.z; wv_c[4*q+3] = v.w;
  }
  float2 sm_c = svmu[lane];
  float xv_c[NB];
#pragma unroll
  for (int i = 0; i < NB; ++i) xv_c[i] = x_lds[w][i][0];

  // ---- layer 1 over all 66 input dims, software-pipelined ----
#pragma unroll 2
  for (int d = 0; d < DD; ++d) {
    const int dn  = (d + 1 < DD) ? d + 1 : DD - 1;
    const int dnn = (d + 2 < DD) ? d + 2 : DD - 1;
    // issue next loads first (noise depth-2, weights/x depth-1)
    float nv2[NB];
#pragma unroll
    for (int i = 0; i < NB; ++i) nv2[i] = np[i][dnn*ZZ];
    float wv_n[16];
#pragma unroll
    for (int q = 0; q < 4; ++q) {
      const float4 v = *reinterpret_cast<const float4*>(w1t + ((dn*4 + q)*64 + lane)*4);
      wv_n[4*q] = v.x; wv_n[4*q+1] = v.y; wv_n[4*q+2] = v.z; wv_n[4*q+3] = v.w;
    }
    const float2 sm_n = svmu[dn*ZZ + lane];
    float xv_n[NB];
#pragma unroll
    for (int i = 0; i < NB; ++i) xv_n[i] = x_lds[w][i][dn];

    // compute iteration d
#pragma unroll
    for (int i = 0; i < NB; ++i) {
      const float mean = xv_c[i] * sm_c.x;
      kacc[i] = fmaf(mean, mean, kacc[i]);
      const float xt = fmaf(nv_c[i], sm_c.y, mean);
#pragma unroll
      for (int h = 0; h < 16; ++h) acc[i][h] = fmaf(xt, wv_c[h], acc[i][h]);
    }
    // rotate
#pragma unroll
    for (int i = 0; i < NB; ++i) { nv_c[i] = nv_n[i]; nv_n[i] = nv2[i]; xv_c[i] = xv_n[i]; }
#pragma unroll
    for (int h = 0; h < 16; ++h) wv_c[h] = wv_n[h];
    sm_c = sm_n;
  }

  // ---- layer 2 (coalesced W2T) ----
  float h2[NB][16];
  {
    const float4* bp = reinterpret_cast<const float4*>(b2 + lane*16);
    float b2r[16];
#pragma unroll
    for (int q = 0; q < 4; ++q) {
      const float4 v = bp[q];
      b2r[4*q] = v.x; b2r[4*q+1] = v.y; b2r[4*q+2] = v.z; b2r[4*q+3] = v.w;
    }
#pragma unroll
    for (int i = 0; i < NB; ++i) {
#pragma unroll
      for (int h = 0; h < 16; ++h) acc[i][h] = fmaxf(acc[i][h], 0.f);
#pragma unroll
      for (int k = 0; k < 16; ++k) h2[i][k] = b2r[k];
    }
  }
  const float* w2t = ws + OFF_W2T;
#pragma unroll
  for (int h = 0; h < 16; ++h) {
    float wv2[16];
#pragma unroll
    for (int q = 0; q < 4; ++q) {
      const float4 v = *reinterpret_cast<const float4*>(w2t + ((h*4 + q)*64 + lane)*4);
      wv2[4*q] = v.x; wv2[4*q+1] = v.y; wv2[4*q+2] = v.z; wv2[4*q+3] = v.w;
    }
#pragma unroll
    for (int i = 0; i < NB; ++i) {
      const float hv = acc[i][h];
#pragma unroll
      for (int k = 0; k < 16; ++k) h2[i][k] = fmaf(hv, wv2[k], h2[i][k]);
    }
  }

  // ---- layer 3 + gate + kld/z_tilde outputs (coalesced W3T) ----
  float w3r[32];
  {
    const float* w3t = ws + OFF_W3T;
#pragma unroll
    for (int q = 0; q < 8; ++q) {
      const float4 v = *reinterpret_cast<const float4*>(w3t + (q*64 + lane)*4);
      w3r[4*q] = v.x; w3r[4*q+1] = v.y; w3r[4*q+2] = v.z; w3r[4*q+3] = v.w;
    }
  }
  const float2 b3v = reinterpret_cast<const float2*>(b3)[lane];
#pragma unroll
  for (int i = 0; i < NB; ++i) {
    const int b = b0 + i;
    float o0 = b3v.x, o1 = b3v.y;
#pragma unroll
    for (int k = 0; k < 16; ++k) {
      const float hv = fmaxf(h2[i][k], 0.f);
      o0 = fmaf(hv, w3r[2*k], o0);
      o1 = fmaf(hv, w3r[2*k + 1], o1);
    }
    const float xl = x_lds[w][i][lane];
    const float wg = 1.f / (1.f + __expf(-o1));
    const float nl = fmaf(wg, o0 - xl, xl);        // (1-w)*lat + u*w
    const float tg = mg_l * nl;
    const float zt = fmaf(noise_g[b*ZZ + lane], svg_l, tg);
    out_zt[b*ZZ + lane] = zt;
    out_ku[b*ZZ + lane] = fmaf(0.5f, kacc[i], c0u_l);
    ztl[w*NB + i][lane] = zt;
    // kld_g: wave-wide butterfly reduce of tg^2 (no LDS, no barrier)
    float t2 = tg * tg;
#pragma unroll
    for (int off = 32; off; off >>= 1) t2 += __shfl_xor(t2, off);
    if (lane == 0) out_kg[b] = fmaf(0.5f, t2, c0g);
  }
  __syncthreads();

  // ---- fused choice MLP: 16 rows x 32 neurons, 256 threads -> 2 row-groups ----
  const int r  = tid >> 5;        // 0..7
  const int hc = tid & 31;
#pragma unroll
  for (int g = 0; g < 2; ++g) {
    const int row = g*8 + r;
    float a = bc1[hc];
#pragma unroll
    for (int zc = 0; zc < 64; ++zc) a = fmaf(ztl[row][zc], Wc1[zc*32 + hc], a);
    y1[row][hc] = fmaxf(a, 0.f);
  }
  __syncthreads();
#pragma unroll
  for (int g = 0; g < 2; ++g) {
    const int row = g*8 + r;
    float a = bc2[hc];
#pragma unroll
    for (int k = 0; k < 32; ++k) a = fmaf(y1[row][k], Wc2[k*32 + hc], a);
    y2[row][hc] = fmaxf(a, 0.f);
  }
  __syncthreads();
  if (tid < ROWS*2) {
    const int rr = tid >> 1, o = tid & 1;
    float s = bc3[o];
#pragma unroll
    for (int k = 0; k < 32; ++k) s = fmaf(y2[rr][k], Wc3[2*k + o], s);
    out[(blockIdx.x*ROWS + rr)*2 + o] = s;
  }
}

extern "C" void kernel_launch(void* const* d_in, const int* in_sizes, int n_in,
                              void* d_out, int out_size, void* d_ws, size_t ws_size,
                              hipStream_t stream) {
  (void)in_sizes; (void)n_in; (void)out_size; (void)ws_size;
  const float* latents  = (const float*)d_in[0];
  const float* obs      = (const float*)d_in[1];
  const float* noise_u  = (const float*)d_in[2];
  const float* noise_g  = (const float*)d_in[3];
  const float* z0       = (const float*)d_in[4];
  const float* mult_u   = (const float*)d_in[5];
  const float* logvar_u = (const float*)d_in[6];
  const float* mult_g   = (const float*)d_in[7];
  const float* logvar_g = (const float*)d_in[8];
  const float* W1       = (const float*)d_in[9];
  const float* b1       = (const float*)d_in[10];
  const float* W2       = (const float*)d_in[11];
  const float* b2       = (const float*)d_in[12];
  const float* W3       = (const float*)d_in[13];
  const float* b3       = (const float*)d_in[14];
  const float* Wc1      = (const float*)d_in[15];
  const float* bc1      = (const float*)d_in[16];
  const float* Wc2      = (const float*)d_in[17];
  const float* bc2      = (const float*)d_in[18];
  const float* Wc3      = (const float*)d_in[19];
  const float* bc3      = (const float*)d_in[20];
  const int*  t0p       = (const int*)d_in[21];
  float* ws   = (float*)d_ws;
  float* outp = (float*)d_out;

  prep_kernel<<<66, 256, 0, stream>>>(mult_u, logvar_u, mult_g, logvar_g, W1, W2, W3, ws);
  disrnn_main<<<BB/ROWS, 256, 0, stream>>>(latents, obs, noise_u, noise_g, z0,
                                           b1, b2, b3, Wc1, bc1, Wc2, bc2, Wc3, bc3,
                                           ws, t0p, outp);
}

// Round 7
// 502.985 us; speedup vs baseline: 1.4571x; 1.1254x over previous
//
#include <hip/hip_runtime.h>
#include <stdint.h>

#define BB 16384
#define ZZ 64
#define DD 66
#define NB 4          // batch rows per wave
#define WPB 4         // waves per block
#define ROWS (WPB*NB) // 16 rows per block

// ---- ws float offsets (filled by prep kernel every launch) ----
#define OFF_SVMU 0            // [66][64] float2 (mult_u, sqrt(var_u)) -> 8448 floats
#define OFF_C0U  8448         // 64 : -0.5*sum_d(1+lv-var) per z
#define OFF_MG   8512         // 64
#define OFF_SVG  8576         // 64
#define OFF_C0G  8640         // 1
#define OFF_W1T  8704         // [66][4][64][4] floats = 67584 (coalesced W1)
#define OFF_W2T  76288        // [16][4][64][4] floats = 16384 (coalesced W2)
#define OFF_W3T  92672        // [8][64][4]    floats = 2048  (coalesced W3)

// Fold exps/constants + transpose weights into lane-coalesced layouts.
__global__ void prep_kernel(const float* __restrict__ mult_u, const float* __restrict__ logvar_u,
                            const float* __restrict__ mult_g, const float* __restrict__ logvar_g,
                            const float* __restrict__ W1, const float* __restrict__ W2,
                            const float* __restrict__ W3, float* __restrict__ ws) {
  const int d = blockIdx.x;   // 0..65
  const int t = threadIdx.x;
  const int z = t >> 2, q = t & 3;

  // W1 transpose: W1T[((d*4+q)*64+z)*4 + j] = W1[(z*DD+d)*16 + q*4 + j]
  {
    const float4 v = *reinterpret_cast<const float4*>(W1 + (z*DD + d)*16 + q*4);
    *reinterpret_cast<float4*>(ws + OFF_W1T + ((d*4 + q)*64 + z)*4) = v;
  }
  if (t < ZZ) {
    ws[OFF_SVMU + 2*(d*ZZ + t)]     = mult_u[d*ZZ + t];
    ws[OFF_SVMU + 2*(d*ZZ + t) + 1] = __expf(0.5f * logvar_u[d*ZZ + t]);
  }
  if (d < 16) {  // W2 transpose, h = d
    const float4 v = *reinterpret_cast<const float4*>(W2 + (z*16 + d)*16 + q*4);
    *reinterpret_cast<float4*>(ws + OFF_W2T + ((d*4 + q)*64 + z)*4) = v;
  }
  if (d == 16 || d == 17) {  // W3 transpose
    const int idx = (d - 16)*256 + t;   // 0..511
    const int qq = idx >> 6, zz = idx & 63;
    const float4 v = *reinterpret_cast<const float4*>(W3 + zz*32 + qq*4);
    *reinterpret_cast<float4*>(ws + OFF_W3T + (qq*64 + zz)*4) = v;
  }
  if (d == 0) {
    if (t < ZZ) {
      float s = 0.f;
      for (int dd = 0; dd < DD; ++dd) {
        const float lv = logvar_u[dd*ZZ + t];
        s += 1.f + lv - __expf(lv);
      }
      ws[OFF_C0U + t] = -0.5f * s;
      ws[OFF_MG  + t] = mult_g[t];
      ws[OFF_SVG + t] = __expf(0.5f * logvar_g[t]);
    }
    if (t == 0) {
      float s = 0.f;
      for (int zc = 0; zc < ZZ; ++zc) {
        const float lv = logvar_g[zc];
        s += 1.f + lv - __expf(lv);
      }
      ws[OFF_C0G] = -0.5f * s;
    }
  }
}

// Main: lane = z; wave handles NB batch rows. Register pipeline in the d-loop
// (noise depth-2, weights/x depth-1); choice MLP fused at block level.
// launch_bounds(256,1): pipeline needs ~150 live VGPRs; (256,2) made the
// allocator clamp to 128 and spill ~170 MB/dispatch to scratch (round-2 PMC:
// WRITE_SIZE 177 MB vs 8.6 MB true outputs). 1 wave/EU min lets it allocate
// freely; expected ~160 VGPR -> 3 waves/SIMD, zero spill.
__global__ __launch_bounds__(256, 1)
void disrnn_main(const float* __restrict__ latents, const float* __restrict__ obs,
                 const float* __restrict__ noise_u, const float* __restrict__ noise_g,
                 const float* __restrict__ z0, const float* __restrict__ b1,
                 const float* __restrict__ b2, const float* __restrict__ b3,
                 const float* __restrict__ Wc1, const float* __restrict__ bc1,
                 const float* __restrict__ Wc2, const float* __restrict__ bc2,
                 const float* __restrict__ Wc3, const float* __restrict__ bc3,
                 const float* __restrict__ ws, const int* __restrict__ t0p,
                 float* __restrict__ out) {
  float* out_zt = out + BB*2;
  float* out_kg = out + BB*2 + BB*ZZ;
  float* out_ku = out + BB*2 + BB*ZZ + BB;

  __shared__ float x_lds[WPB][NB][68];
  __shared__ float ztl[ROWS][64];
  __shared__ float y1[ROWS][32];
  __shared__ float y2[ROWS][32];

  const int tid  = threadIdx.x;
  const int w    = tid >> 6;
  const int lane = tid & 63;
  const int b0   = (blockIdx.x * WPB + w) * NB;
  const int t0   = *t0p;

#pragma unroll
  for (int i = 0; i < NB; ++i) {
    x_lds[w][i][lane] = t0 ? z0[lane] : latents[(b0 + i)*ZZ + lane];
    if (lane < 2) x_lds[w][i][ZZ + lane] = obs[(b0 + i)*2 + lane];
  }
  __syncthreads();

  const float c0u_l = ws[OFF_C0U + lane];
  const float mg_l  = ws[OFF_MG + lane];
  const float svg_l = ws[OFF_SVG + lane];
  const float c0g   = ws[OFF_C0G];

  float acc[NB][16], kacc[NB];
  {
    const float4* bp = reinterpret_cast<const float4*>(b1 + lane*16);
    float b1r[16];
#pragma unroll
    for (int q = 0; q < 4; ++q) {
      const float4 v = bp[q];
      b1r[4*q] = v.x; b1r[4*q+1] = v.y; b1r[4*q+2] = v.z; b1r[4*q+3] = v.w;
    }
#pragma unroll
    for (int i = 0; i < NB; ++i) {
      kacc[i] = 0.f;
#pragma unroll
      for (int h = 0; h < 16; ++h) acc[i][h] = b1r[h];
    }
  }

  const float*  w1t  = ws + OFF_W1T;
  const float2* svmu = reinterpret_cast<const float2*>(ws + OFF_SVMU);
  const float* np[NB];
#pragma unroll
  for (int i = 0; i < NB; ++i) np[i] = noise_u + (b0 + i)*DD*ZZ + lane;

  // ---- pipeline prologue ----
  float nv_c[NB], nv_n[NB];
#pragma unroll
  for (int i = 0; i < NB; ++i) { nv_c[i] = np[i][0]; nv_n[i] = np[i][ZZ]; }
  float wv_c[16];
#pragma unroll
  for (int q = 0; q < 4; ++q) {
    const float4 v = *reinterpret_cast<const float4*>(w1t + (q*64 + lane)*4);
    wv_c[4*q] = v.x; wv_c[4*q+1] = v.y; wv_c[4*q+2] = v.z; wv_c[4*q+3] = v.w;
  }
  float2 sm_c = svmu[lane];
  float xv_c[NB];
#pragma unroll
  for (int i = 0; i < NB; ++i) xv_c[i] = x_lds[w][i][0];

  // ---- layer 1 over all 66 input dims, software-pipelined ----
#pragma unroll 2
  for (int d = 0; d < DD; ++d) {
    const int dn  = (d + 1 < DD) ? d + 1 : DD - 1;
    const int dnn = (d + 2 < DD) ? d + 2 : DD - 1;
    // issue next loads first (noise depth-2, weights/x depth-1)
    float nv2[NB];
#pragma unroll
    for (int i = 0; i < NB; ++i) nv2[i] = np[i][dnn*ZZ];
    float wv_n[16];
#pragma unroll
    for (int q = 0; q < 4; ++q) {
      const float4 v = *reinterpret_cast<const float4*>(w1t + ((dn*4 + q)*64 + lane)*4);
      wv_n[4*q] = v.x; wv_n[4*q+1] = v.y; wv_n[4*q+2] = v.z; wv_n[4*q+3] = v.w;
    }
    const float2 sm_n = svmu[dn*ZZ + lane];
    float xv_n[NB];
#pragma unroll
    for (int i = 0; i < NB; ++i) xv_n[i] = x_lds[w][i][dn];

    // compute iteration d
#pragma unroll
    for (int i = 0; i < NB; ++i) {
      const float mean = xv_c[i] * sm_c.x;
      kacc[i] = fmaf(mean, mean, kacc[i]);
      const float xt = fmaf(nv_c[i], sm_c.y, mean);
#pragma unroll
      for (int h = 0; h < 16; ++h) acc[i][h] = fmaf(xt, wv_c[h], acc[i][h]);
    }
    // rotate
#pragma unroll
    for (int i = 0; i < NB; ++i) { nv_c[i] = nv_n[i]; nv_n[i] = nv2[i]; xv_c[i] = xv_n[i]; }
#pragma unroll
    for (int h = 0; h < 16; ++h) wv_c[h] = wv_n[h];
    sm_c = sm_n;
  }

  // ---- layer 2 (coalesced W2T) ----
  float h2[NB][16];
  {
    const float4* bp = reinterpret_cast<const float4*>(b2 + lane*16);
    float b2r[16];
#pragma unroll
    for (int q = 0; q < 4; ++q) {
      const float4 v = bp[q];
      b2r[4*q] = v.x; b2r[4*q+1] = v.y; b2r[4*q+2] = v.z; b2r[4*q+3] = v.w;
    }
#pragma unroll
    for (int i = 0; i < NB; ++i) {
#pragma unroll
      for (int h = 0; h < 16; ++h) acc[i][h] = fmaxf(acc[i][h], 0.f);
#pragma unroll
      for (int k = 0; k < 16; ++k) h2[i][k] = b2r[k];
    }
  }
  const float* w2t = ws + OFF_W2T;
#pragma unroll
  for (int h = 0; h < 16; ++h) {
    float wv2[16];
#pragma unroll
    for (int q = 0; q < 4; ++q) {
      const float4 v = *reinterpret_cast<const float4*>(w2t + ((h*4 + q)*64 + lane)*4);
      wv2[4*q] = v.x; wv2[4*q+1] = v.y; wv2[4*q+2] = v.z; wv2[4*q+3] = v.w;
    }
#pragma unroll
    for (int i = 0; i < NB; ++i) {
      const float hv = acc[i][h];
#pragma unroll
      for (int k = 0; k < 16; ++k) h2[i][k] = fmaf(hv, wv2[k], h2[i][k]);
    }
  }

  // ---- layer 3 + gate + kld/z_tilde outputs (coalesced W3T) ----
  float w3r[32];
  {
    const float* w3t = ws + OFF_W3T;
#pragma unroll
    for (int q = 0; q < 8; ++q) {
      const float4 v = *reinterpret_cast<const float4*>(w3t + (q*64 + lane)*4);
      w3r[4*q] = v.x; w3r[4*q+1] = v.y; w3r[4*q+2] = v.z; w3r[4*q+3] = v.w;
    }
  }
  const float2 b3v = reinterpret_cast<const float2*>(b3)[lane];
#pragma unroll
  for (int i = 0; i < NB; ++i) {
    const int b = b0 + i;
    float o0 = b3v.x, o1 = b3v.y;
#pragma unroll
    for (int k = 0; k < 16; ++k) {
      const float hv = fmaxf(h2[i][k], 0.f);
      o0 = fmaf(hv, w3r[2*k], o0);
      o1 = fmaf(hv, w3r[2*k + 1], o1);
    }
    const float xl = x_lds[w][i][lane];
    const float wg = 1.f / (1.f + __expf(-o1));
    const float nl = fmaf(wg, o0 - xl, xl);        // (1-w)*lat + u*w
    const float tg = mg_l * nl;
    const float zt = fmaf(noise_g[b*ZZ + lane], svg_l, tg);
    out_zt[b*ZZ + lane] = zt;
    out_ku[b*ZZ + lane] = fmaf(0.5f, kacc[i], c0u_l);
    ztl[w*NB + i][lane] = zt;
    // kld_g: wave-wide butterfly reduce of tg^2 (no LDS, no barrier)
    float t2 = tg * tg;
#pragma unroll
    for (int off = 32; off; off >>= 1) t2 += __shfl_xor(t2, off);
    if (lane == 0) out_kg[b] = fmaf(0.5f, t2, c0g);
  }
  __syncthreads();

  // ---- fused choice MLP: 16 rows x 32 neurons, 256 threads -> 2 row-groups ----
  const int r  = tid >> 5;        // 0..7
  const int hc = tid & 31;
#pragma unroll
  for (int g = 0; g < 2; ++g) {
    const int row = g*8 + r;
    float a = bc1[hc];
#pragma unroll
    for (int zc = 0; zc < 64; ++zc) a = fmaf(ztl[row][zc], Wc1[zc*32 + hc], a);
    y1[row][hc] = fmaxf(a, 0.f);
  }
  __syncthreads();
#pragma unroll
  for (int g = 0; g < 2; ++g) {
    const int row = g*8 + r;
    float a = bc2[hc];
#pragma unroll
    for (int k = 0; k < 32; ++k) a = fmaf(y1[row][k], Wc2[k*32 + hc], a);
    y2[row][hc] = fmaxf(a, 0.f);
  }
  __syncthreads();
  if (tid < ROWS*2) {
    const int rr = tid >> 1, o = tid & 1;
    float s = bc3[o];
#pragma unroll
    for (int k = 0; k < 32; ++k) s = fmaf(y2[rr][k], Wc3[2*k + o], s);
    out[(blockIdx.x*ROWS + rr)*2 + o] = s;
  }
}

extern "C" void kernel_launch(void* const* d_in, const int* in_sizes, int n_in,
                              void* d_out, int out_size, void* d_ws, size_t ws_size,
                              hipStream_t stream) {
  (void)in_sizes; (void)n_in; (void)out_size; (void)ws_size;
  const float* latents  = (const float*)d_in[0];
  const float* obs      = (const float*)d_in[1];
  const float* noise_u  = (const float*)d_in[2];
  const float* noise_g  = (const float*)d_in[3];
  const float* z0       = (const float*)d_in[4];
  const float* mult_u   = (const float*)d_in[5];
  const float* logvar_u = (const float*)d_in[6];
  const float* mult_g   = (const float*)d_in[7];
  const float* logvar_g = (const float*)d_in[8];
  const float* W1       = (const float*)d_in[9];
  const float* b1       = (const float*)d_in[10];
  const float* W2       = (const float*)d_in[11];
  const float* b2       = (const float*)d_in[12];
  const float* W3       = (const float*)d_in[13];
  const float* b3       = (const float*)d_in[14];
  const float* Wc1      = (const float*)d_in[15];
  const float* bc1      = (const float*)d_in[16];
  const float* Wc2      = (const float*)d_in[17];
  const float* bc2      = (const float*)d_in[18];
  const float* Wc3      = (const float*)d_in[19];
  const float* bc3      = (const float*)d_in[20];
  const int*  t0p       = (const int*)d_in[21];
  float* ws   = (float*)d_ws;
  float* outp = (float*)d_out;

  prep_kernel<<<66, 256, 0, stream>>>(mult_u, logvar_u, mult_g, logvar_g, W1, W2, W3, ws);
  disrnn_main<<<BB/ROWS, 256, 0, stream>>>(latents, obs, noise_u, noise_g, z0,
                                           b1, b2, b3, Wc1, bc1, Wc2, bc2, Wc3, bc3,
                                           ws, t0p, outp);
}

// Round 8
// 500.926 us; speedup vs baseline: 1.4631x; 1.0041x over previous
//
#include <hip/hip_runtime.h>
#include <stdint.h>

#define BB 16384
#define ZZ 64
#define DD 66
#define NB 4          // batch rows per wave
#define WPB 4         // waves per block
#define ROWS (WPB*NB) // 16 rows per block

// ---- ws float offsets (filled by prep kernel every launch) ----
#define OFF_SVMU 0            // [66][64] float2 (mult_u, sqrt(var_u)) -> 8448 floats
#define OFF_C0U  8448         // 64 : -0.5*sum_d(1+lv-var) per z
#define OFF_MG   8512         // 64
#define OFF_SVG  8576         // 64
#define OFF_C0G  8640         // 1
#define OFF_W1T  8704         // [66][4][64][4] floats = 67584 (coalesced W1)
#define OFF_W2T  76288        // [16][4][64][4] floats = 16384 (coalesced W2)
#define OFF_W3T  92672        // [8][64][4]    floats = 2048  (coalesced W3)

// Fold exps/constants + transpose weights into lane-coalesced layouts.
__global__ void prep_kernel(const float* __restrict__ mult_u, const float* __restrict__ logvar_u,
                            const float* __restrict__ mult_g, const float* __restrict__ logvar_g,
                            const float* __restrict__ W1, const float* __restrict__ W2,
                            const float* __restrict__ W3, float* __restrict__ ws) {
  const int d = blockIdx.x;   // 0..65
  const int t = threadIdx.x;
  const int z = t >> 2, q = t & 3;

  // W1 transpose: W1T[((d*4+q)*64+z)*4 + j] = W1[(z*DD+d)*16 + q*4 + j]
  {
    const float4 v = *reinterpret_cast<const float4*>(W1 + (z*DD + d)*16 + q*4);
    *reinterpret_cast<float4*>(ws + OFF_W1T + ((d*4 + q)*64 + z)*4) = v;
  }
  if (t < ZZ) {
    ws[OFF_SVMU + 2*(d*ZZ + t)]     = mult_u[d*ZZ + t];
    ws[OFF_SVMU + 2*(d*ZZ + t) + 1] = __expf(0.5f * logvar_u[d*ZZ + t]);
  }
  if (d < 16) {  // W2 transpose, h = d
    const float4 v = *reinterpret_cast<const float4*>(W2 + (z*16 + d)*16 + q*4);
    *reinterpret_cast<float4*>(ws + OFF_W2T + ((d*4 + q)*64 + z)*4) = v;
  }
  if (d == 16 || d == 17) {  // W3 transpose
    const int idx = (d - 16)*256 + t;   // 0..511
    const int qq = idx >> 6, zz = idx & 63;
    const float4 v = *reinterpret_cast<const float4*>(W3 + zz*32 + qq*4);
    *reinterpret_cast<float4*>(ws + OFF_W3T + (qq*64 + zz)*4) = v;
  }
  if (d == 0) {
    if (t < ZZ) {
      float s = 0.f;
      for (int dd = 0; dd < DD; ++dd) {
        const float lv = logvar_u[dd*ZZ + t];
        s += 1.f + lv - __expf(lv);
      }
      ws[OFF_C0U + t] = -0.5f * s;
      ws[OFF_MG  + t] = mult_g[t];
      ws[OFF_SVG + t] = __expf(0.5f * logvar_g[t]);
    }
    if (t == 0) {
      float s = 0.f;
      for (int zc = 0; zc < ZZ; ++zc) {
        const float lv = logvar_g[zc];
        s += 1.f + lv - __expf(lv);
      }
      ws[OFF_C0G] = -0.5f * s;
    }
  }
}

// Main: lane = z; wave handles NB batch rows.
// Noise stream: dwordx4 chunk staging (4 d-rows / load) through a per-wave LDS
// double buffer -> 4 KB in flight per wave (vs 32 B scalar depth-2 in r7),
// fixing the Little's-law shortfall that left the kernel 80% stalled.
// No barriers: buffers are wave-private; same-wave DS ordering is preserved
// by the compiler (same __shared__ array).
// launch_bounds(256,1): r7 PMC proved (256,2) spills (~170 MB scratch) and
// (256,1) does not (WRITE_SIZE 8.4 MB, VGPR 200).
__global__ __launch_bounds__(256, 1)
void disrnn_main(const float* __restrict__ latents, const float* __restrict__ obs,
                 const float* __restrict__ noise_u, const float* __restrict__ noise_g,
                 const float* __restrict__ z0, const float* __restrict__ b1,
                 const float* __restrict__ b2, const float* __restrict__ b3,
                 const float* __restrict__ Wc1, const float* __restrict__ bc1,
                 const float* __restrict__ Wc2, const float* __restrict__ bc2,
                 const float* __restrict__ Wc3, const float* __restrict__ bc3,
                 const float* __restrict__ ws, const int* __restrict__ t0p,
                 float* __restrict__ out) {
  float* out_zt = out + BB*2;
  float* out_kg = out + BB*2 + BB*ZZ;
  float* out_ku = out + BB*2 + BB*ZZ + BB;

  __shared__ float x_lds[WPB][NB][68];
  __shared__ float noise_lds[WPB][2][NB][4*ZZ];   // 32 KB: per-wave double buffer
  __shared__ float ztl[ROWS][64];
  __shared__ float y1[ROWS][32];
  __shared__ float y2[ROWS][32];

  const int tid  = threadIdx.x;
  const int w    = tid >> 6;
  const int lane = tid & 63;
  const int b0   = (blockIdx.x * WPB + w) * NB;
  const int t0   = *t0p;

#pragma unroll
  for (int i = 0; i < NB; ++i) {
    x_lds[w][i][lane] = t0 ? z0[lane] : latents[(b0 + i)*ZZ + lane];
    if (lane < 2) x_lds[w][i][ZZ + lane] = obs[(b0 + i)*2 + lane];
  }
  __syncthreads();

  const float c0u_l = ws[OFF_C0U + lane];
  const float mg_l  = ws[OFF_MG + lane];
  const float svg_l = ws[OFF_SVG + lane];
  const float c0g   = ws[OFF_C0G];

  float acc[NB][16], kacc[NB];
  {
    const float4* bp = reinterpret_cast<const float4*>(b1 + lane*16);
    float b1r[16];
#pragma unroll
    for (int q = 0; q < 4; ++q) {
      const float4 v = bp[q];
      b1r[4*q] = v.x; b1r[4*q+1] = v.y; b1r[4*q+2] = v.z; b1r[4*q+3] = v.w;
    }
#pragma unroll
    for (int i = 0; i < NB; ++i) {
      kacc[i] = 0.f;
#pragma unroll
      for (int h = 0; h < 16; ++h) acc[i][h] = b1r[h];
    }
  }

  const float*  w1t  = ws + OFF_W1T;
  const float2* svmu = reinterpret_cast<const float2*>(ws + OFF_SVMU);

  // ---- noise chunk staging: chunk c covers d = 4c..4c+3 ----
  // lane reads 16 B at row-block offset lane*4 floats -> row d0 + lane/16.
  const int dsub = lane >> 4;
  float4 st[NB];
  {
    // prologue: stage chunk 0 into buffer 0
#pragma unroll
    for (int i = 0; i < NB; ++i)
      st[i] = *reinterpret_cast<const float4*>(
          noise_u + ((size_t)(b0 + i)*DD + 0)*ZZ + lane*4);
#pragma unroll
    for (int i = 0; i < NB; ++i)
      *reinterpret_cast<float4*>(&noise_lds[w][0][i][lane*4]) = st[i];
  }
  int cur = 0;

  // ---- weight/x pipeline prologue (depth-1, unchanged from r7) ----
  float wv_c[16];
#pragma unroll
  for (int q = 0; q < 4; ++q) {
    const float4 v = *reinterpret_cast<const float4*>(w1t + (q*64 + lane)*4);
    wv_c[4*q] = v.x; wv_c[4*q+1] = v.y; wv_c[4*q+2] = v.z; wv_c[4*q+3] = v.w;
  }
  float2 sm_c = svmu[lane];
  float xv_c[NB];
#pragma unroll
  for (int i = 0; i < NB; ++i) xv_c[i] = x_lds[w][i][0];

  // ---- main loop: 16 chunks of 4 d's (d = 0..63) ----
  for (int c = 0; c < 16; ++c) {
    // issue next chunk's noise loads (HBM latency hides under this chunk's compute)
    {
      const int d0n = (c + 1) * 4;
#pragma unroll
      for (int i = 0; i < NB; ++i) {
        st[i] = make_float4(0.f, 0.f, 0.f, 0.f);
        if (d0n + dsub < DD)   // tail chunk (c+1==16) has only 2 valid rows
          st[i] = *reinterpret_cast<const float4*>(
              noise_u + ((size_t)(b0 + i)*DD + d0n)*ZZ + lane*4);
      }
    }
    // pull this chunk's noise LDS -> regs (conflict-free stride-1 reads)
    float nvv[4][NB];
#pragma unroll
    for (int j = 0; j < 4; ++j)
#pragma unroll
      for (int i = 0; i < NB; ++i)
        nvv[j][i] = noise_lds[w][cur][i][j*ZZ + lane];

#pragma unroll
    for (int j = 0; j < 4; ++j) {
      const int d  = c*4 + j;
      const int dn = d + 1;              // <= 64 here, always valid
      // weight/x depth-1 prefetch
      float wv_n[16];
#pragma unroll
      for (int q = 0; q < 4; ++q) {
        const float4 v = *reinterpret_cast<const float4*>(w1t + ((dn*4 + q)*64 + lane)*4);
        wv_n[4*q] = v.x; wv_n[4*q+1] = v.y; wv_n[4*q+2] = v.z; wv_n[4*q+3] = v.w;
      }
      const float2 sm_n = svmu[dn*ZZ + lane];
      float xv_n[NB];
#pragma unroll
      for (int i = 0; i < NB; ++i) xv_n[i] = x_lds[w][i][dn];
      // compute iteration d
#pragma unroll
      for (int i = 0; i < NB; ++i) {
        const float mean = xv_c[i] * sm_c.x;
        kacc[i] = fmaf(mean, mean, kacc[i]);
        const float xt = fmaf(nvv[j][i], sm_c.y, mean);
#pragma unroll
        for (int h = 0; h < 16; ++h) acc[i][h] = fmaf(xt, wv_c[h], acc[i][h]);
      }
      // rotate
#pragma unroll
      for (int h = 0; h < 16; ++h) wv_c[h] = wv_n[h];
      sm_c = sm_n;
#pragma unroll
      for (int i = 0; i < NB; ++i) xv_c[i] = xv_n[i];
    }
    // commit next chunk to the other buffer (vmcnt wait via register dep)
#pragma unroll
    for (int i = 0; i < NB; ++i)
      *reinterpret_cast<float4*>(&noise_lds[w][cur ^ 1][i][lane*4]) = st[i];
    cur ^= 1;
  }

  // ---- tail: d = 64, 65 (chunk 16, staged during c=15) ----
  {
    float nvt[2][NB];
#pragma unroll
    for (int j = 0; j < 2; ++j)
#pragma unroll
      for (int i = 0; i < NB; ++i)
        nvt[j][i] = noise_lds[w][cur][i][j*ZZ + lane];
#pragma unroll
    for (int j = 0; j < 2; ++j) {
      const int d  = 64 + j;
      const int dn = (d + 1 < DD) ? d + 1 : DD - 1;
      float wv_n[16];
#pragma unroll
      for (int q = 0; q < 4; ++q) {
        const float4 v = *reinterpret_cast<const float4*>(w1t + ((dn*4 + q)*64 + lane)*4);
        wv_n[4*q] = v.x; wv_n[4*q+1] = v.y; wv_n[4*q+2] = v.z; wv_n[4*q+3] = v.w;
      }
      const float2 sm_n = svmu[dn*ZZ + lane];
#pragma unroll
      for (int i = 0; i < NB; ++i) {
        const float mean = xv_c[i] * sm_c.x;
        kacc[i] = fmaf(mean, mean, kacc[i]);
        const float xt = fmaf(nvt[j][i], sm_c.y, mean);
#pragma unroll
        for (int h = 0; h < 16; ++h) acc[i][h] = fmaf(xt, wv_c[h], acc[i][h]);
      }
#pragma unroll
      for (int h = 0; h < 16; ++h) wv_c[h] = wv_n[h];
      sm_c = sm_n;
#pragma unroll
      for (int i = 0; i < NB; ++i) xv_c[i] = x_lds[w][i][dn];
    }
  }

  // ---- layer 2 (coalesced W2T) ----
  float h2[NB][16];
  {
    const float4* bp = reinterpret_cast<const float4*>(b2 + lane*16);
    float b2r[16];
#pragma unroll
    for (int q = 0; q < 4; ++q) {
      const float4 v = bp[q];
      b2r[4*q] = v.x; b2r[4*q+1] = v.y; b2r[4*q+2] = v.z; b2r[4*q+3] = v.w;
    }
#pragma unroll
    for (int i = 0; i < NB; ++i) {
#pragma unroll
      for (int h = 0; h < 16; ++h) acc[i][h] = fmaxf(acc[i][h], 0.f);
#pragma unroll
      for (int k = 0; k < 16; ++k) h2[i][k] = b2r[k];
    }
  }
  const float* w2t = ws + OFF_W2T;
#pragma unroll
  for (int h = 0; h < 16; ++h) {
    float wv2[16];
#pragma unroll
    for (int q = 0; q < 4; ++q) {
      const float4 v = *reinterpret_cast<const float4*>(w2t + ((h*4 + q)*64 + lane)*4);
      wv2[4*q] = v.x; wv2[4*q+1] = v.y; wv2[4*q+2] = v.z; wv2[4*q+3] = v.w;
    }
#pragma unroll
    for (int i = 0; i < NB; ++i) {
      const float hv = acc[i][h];
#pragma unroll
      for (int k = 0; k < 16; ++k) h2[i][k] = fmaf(hv, wv2[k], h2[i][k]);
    }
  }

  // ---- layer 3 + gate + kld/z_tilde outputs (coalesced W3T) ----
  float w3r[32];
  {
    const float* w3t = ws + OFF_W3T;
#pragma unroll
    for (int q = 0; q < 8; ++q) {
      const float4 v = *reinterpret_cast<const float4*>(w3t + (q*64 + lane)*4);
      w3r[4*q] = v.x; w3r[4*q+1] = v.y; w3r[4*q+2] = v.z; w3r[4*q+3] = v.w;
    }
  }
  const float2 b3v = reinterpret_cast<const float2*>(b3)[lane];
#pragma unroll
  for (int i = 0; i < NB; ++i) {
    const int b = b0 + i;
    float o0 = b3v.x, o1 = b3v.y;
#pragma unroll
    for (int k = 0; k < 16; ++k) {
      const float hv = fmaxf(h2[i][k], 0.f);
      o0 = fmaf(hv, w3r[2*k], o0);
      o1 = fmaf(hv, w3r[2*k + 1], o1);
    }
    const float xl = x_lds[w][i][lane];
    const float wg = 1.f / (1.f + __expf(-o1));
    const float nl = fmaf(wg, o0 - xl, xl);        // (1-w)*lat + u*w
    const float tg = mg_l * nl;
    const float zt = fmaf(noise_g[b*ZZ + lane], svg_l, tg);
    out_zt[b*ZZ + lane] = zt;
    out_ku[b*ZZ + lane] = fmaf(0.5f, kacc[i], c0u_l);
    ztl[w*NB + i][lane] = zt;
    // kld_g: wave-wide butterfly reduce of tg^2 (no LDS, no barrier)
    float t2 = tg * tg;
#pragma unroll
    for (int off = 32; off; off >>= 1) t2 += __shfl_xor(t2, off);
    if (lane == 0) out_kg[b] = fmaf(0.5f, t2, c0g);
  }
  __syncthreads();

  // ---- fused choice MLP: 16 rows x 32 neurons, 256 threads -> 2 row-groups ----
  const int r  = tid >> 5;        // 0..7
  const int hc = tid & 31;
#pragma unroll
  for (int g = 0; g < 2; ++g) {
    const int row = g*8 + r;
    float a = bc1[hc];
#pragma unroll
    for (int zc = 0; zc < 64; ++zc) a = fmaf(ztl[row][zc], Wc1[zc*32 + hc], a);
    y1[row][hc] = fmaxf(a, 0.f);
  }
  __syncthreads();
#pragma unroll
  for (int g = 0; g < 2; ++g) {
    const int row = g*8 + r;
    float a = bc2[hc];
#pragma unroll
    for (int k = 0; k < 32; ++k) a = fmaf(y1[row][k], Wc2[k*32 + hc], a);
    y2[row][hc] = fmaxf(a, 0.f);
  }
  __syncthreads();
  if (tid < ROWS*2) {
    const int rr = tid >> 1, o = tid & 1;
    float s = bc3[o];
#pragma unroll
    for (int k = 0; k < 32; ++k) s = fmaf(y2[rr][k], Wc3[2*k + o], s);
    out[(blockIdx.x*ROWS + rr)*2 + o] = s;
  }
}

extern "C" void kernel_launch(void* const* d_in, const int* in_sizes, int n_in,
                              void* d_out, int out_size, void* d_ws, size_t ws_size,
                              hipStream_t stream) {
  (void)in_sizes; (void)n_in; (void)out_size; (void)ws_size;
  const float* latents  = (const float*)d_in[0];
  const float* obs      = (const float*)d_in[1];
  const float* noise_u  = (const float*)d_in[2];
  const float* noise_g  = (const float*)d_in[3];
  const float* z0       = (const float*)d_in[4];
  const float* mult_u   = (const float*)d_in[5];
  const float* logvar_u = (const float*)d_in[6];
  const float* mult_g   = (const float*)d_in[7];
  const float* logvar_g = (const float*)d_in[8];
  const float* W1       = (const float*)d_in[9];
  const float* b1       = (const float*)d_in[10];
  const float* W2       = (const float*)d_in[11];
  const float* b2       = (const float*)d_in[12];
  const float* W3       = (const float*)d_in[13];
  const float* b3       = (const float*)d_in[14];
  const float* Wc1      = (const float*)d_in[15];
  const float* bc1      = (const float*)d_in[16];
  const float* Wc2      = (const float*)d_in[17];
  const float* bc2      = (const float*)d_in[18];
  const float* Wc3      = (const float*)d_in[19];
  const float* bc3      = (const float*)d_in[20];
  const int*  t0p       = (const int*)d_in[21];
  float* ws   = (float*)d_ws;
  float* outp = (float*)d_out;

  prep_kernel<<<66, 256, 0, stream>>>(mult_u, logvar_u, mult_g, logvar_g, W1, W2, W3, ws);
  disrnn_main<<<BB/ROWS, 256, 0, stream>>>(latents, obs, noise_u, noise_g, z0,
                                           b1, b2, b3, Wc1, bc1, Wc2, bc2, Wc3, bc3,
                                           ws, t0p, outp);
}